// Round 13
// baseline (118.620 us; speedup 1.0000x reference)
//
#include <hip/hip_runtime.h>

constexpr int K   = 49;    // 7x7 kernel flattened
constexpr int C   = 32;    // out channels
constexpr int BLK = 128;   // 2 waves/block; both waves share the same 64 rows

// 4-byte-aligned float4 (row base w*196 B is only dword-aligned; gfx950
// handles unaligned dwordx4 in HW).
typedef float v4 __attribute__((ext_vector_type(4), aligned(4)));

// Register-pipelined direct kernel. The three proven ingredients plus the
// one new idea:
//  - single temporal load burst (R7: chunked ISSUE re-fetches lines, +75% FETCH)
//  - k-chunk-outer / c-inner CONSUMPTION (R6 flaw: c-outer touches x[48]
//    immediately -> full 13-load drain before 97% of compute). Chunk q needs
//    only loads 3q..3q+2 -> compiler emits progressive vmcnt waits, 192 FMAs
//    overlap the still-in-flight later loads.
//  - 16 ch/thread, readfirstlane-uniform weight base -> scalar s_load weights
//    (R3/R5/R8 root cause), 2 waves of a block re-read the same rows via L1/L2.
//  - no LDS, no barriers, no launch_bounds VGPR cap (R11: forced cap -> spill).
__global__ __launch_bounds__(BLK) void conv2d_regpipe(
    const float* __restrict__ enc_x,
    const float* __restrict__ weight,   // [C*K]
    const float* __restrict__ bias,     // [C]
    float* __restrict__ out,            // [C * windows_nb]
    int windows_nb)
{
    const int t    = threadIdx.x;
    const int lane = t & 63;
    const int wuni = __builtin_amdgcn_readfirstlane(t >> 6);   // 0 or 1, SGPR
    const int c0   = wuni * 16;

    const size_t w = (size_t)blockIdx.x * 64 + lane;           // 64 windows/block
    const float* __restrict__ row = enc_x + w * (size_t)K;

    // ---- single burst: 12 x dwordx4 + 1 scalar, back-to-back ----
    v4 xv[12];
#pragma unroll
    for (int r = 0; r < 12; ++r)
        xv[r] = *reinterpret_cast<const v4*>(row + r * 4);
    const float x48 = row[48];          // exact end of row, no overread

    const float* __restrict__ wp = weight + c0 * K;            // SGPR base
    float acc[16];
#pragma unroll
    for (int cc = 0; cc < 16; ++cc) acc[cc] = bias[c0 + cc];   // scalar loads

    // ---- chunked consumption: chunk q = k[12q .. 12q+11] = loads 3q..3q+2 ----
#pragma unroll
    for (int q = 0; q < 4; ++q) {
#pragma unroll
        for (int cc = 0; cc < 16; ++cc) {
            const float* __restrict__ wc = wp + cc * K + q * 12;  // 12 consecutive -> wide s_load
            float a = acc[cc];
#pragma unroll
            for (int r = 0; r < 3; ++r)
#pragma unroll
                for (int i = 0; i < 4; ++i)
                    a = fmaf(xv[q * 3 + r][i], wc[r * 4 + i], a);
            acc[cc] = a;
        }
    }
    // k = 48 tail
#pragma unroll
    for (int cc = 0; cc < 16; ++cc)
        acc[cc] = fmaf(x48, wp[cc * K + 48], acc[cc]);

    // 16 stores from distinct regs, nothing redefined after -> no store waits.
#pragma unroll
    for (int cc = 0; cc < 16; ++cc)
        out[(size_t)(c0 + cc) * windows_nb + w] = acc[cc];
}

extern "C" void kernel_launch(void* const* d_in, const int* in_sizes, int n_in,
                              void* d_out, int out_size, void* d_ws, size_t ws_size,
                              hipStream_t stream) {
    const float* enc_x  = (const float*)d_in[0];
    const float* weight = (const float*)d_in[1];   // [C,7,7] flat
    const float* bias   = (const float*)d_in[2];   // [C]
    float* out = (float*)d_out;

    const int windows_nb = in_sizes[0] / K;        // 1048576 (divisible by 64)
    const int nblocks = windows_nb / 64;           // 16384

    conv2d_regpipe<<<nblocks, BLK, 0, stream>>>(enc_x, weight, bias, out, windows_nb);
}

// Round 14
// 79.600 us; speedup vs baseline: 1.4902x; 1.4902x over previous
//
#include <hip/hip_runtime.h>
#include <hip/hip_bf16.h>
#include <stdint.h>

constexpr int K      = 49;            // 7x7 kernel flattened
constexpr int KP     = 64;            // K padded for MFMA (2 x 32)
constexpr int C      = 32;            // out channels
constexpr int TILE   = 64;            // windows per block
constexpr int TILE_F = TILE * K;      // 3136 f32 = 12544 B
constexpr int BLK    = 256;           // 4 waves

typedef short bf16x8 __attribute__((ext_vector_type(8)));
typedef float f32x4  __attribute__((ext_vector_type(4)));

#define GPTR(p) ((const __attribute__((address_space(1))) uint32_t*)(p))
#define LPTR(p) ((__attribute__((address_space(3))) uint32_t*)(p))

static __device__ __forceinline__ short f2bf(float f) {
    __hip_bfloat16 h = __float2bfloat16(f);      // RNE
    return __builtin_bit_cast(short, h);
}

// MFMA kernel: compute moves to the matrix pipe so waves return to the
// memory phase ~6x sooner; 32 waves/CU of decorrelated stage-drain phases.
__global__ __launch_bounds__(BLK) void conv2d_mfma(
    const float* __restrict__ enc_x,
    const float* __restrict__ weight,   // [C*K]
    const float* __restrict__ bias,     // [C]
    float* __restrict__ out,            // [C * windows_nb]
    int windows_nb)
{
    // xs (staging, 12608 B) overlaid by cs (C-transpose, 8448 B) after a barrier.
    __shared__ __align__(16) union {
        float xs[TILE_F + 16];          // +16: zero pad for k-overflow reads
        float cs[C * 65 + 16];          // stride 65 breaks store-scatter conflicts
    } sh;
    __shared__ __align__(16) __hip_bfloat16 wlds[C][72];   // k-padded weight palette

    const int t    = threadIdx.x;
    const int lane = t & 63;
    const int lo   = lane & 15, hi = lane >> 4;
    const int wuni = __builtin_amdgcn_readfirstlane(t >> 6);  // SGPR wave id
    const size_t b = blockIdx.x;
    const float* __restrict__ g = enc_x + b * (size_t)TILE_F;

    // ---- stage x-tile (12544 B) via global_load_lds, split over 4 waves ----
    {
        const int widv = t >> 6;                 // divergent ok: staging only
        if (widv < 3) {
#pragma unroll
            for (int r = 0; r < 3; ++r) {
                const int rr = widv * 3 + r;
                __builtin_amdgcn_global_load_lds(GPTR(g + rr * 256 + lane * 4),
                                                 LPTR(sh.xs + rr * 256 + lane * 4), 16, 0, 0);
            }
        } else {
#pragma unroll
            for (int rr = 9; rr < 12; ++rr)
                __builtin_amdgcn_global_load_lds(GPTR(g + rr * 256 + lane * 4),
                                                 LPTR(sh.xs + rr * 256 + lane * 4), 16, 0, 0);
            __builtin_amdgcn_global_load_lds(GPTR(g + 3072 + lane),
                                             LPTR(sh.xs + 3072 + lane), 4, 0, 0);
        }
    }
    if (t < 16) sh.xs[TILE_F + t] = 0.f;         // zero the k-overflow pad

    // ---- build bf16 weight palette wlds[c][0..63] (k>=49 -> 0) ----
    {
        const int c  = t >> 3;                   // 256 threads x 8 = 2048 entries
        const int k0 = (t & 7) * 8;
        __hip_bfloat16 tmp[8];
#pragma unroll
        for (int e = 0; e < 8; ++e) {
            const int k = k0 + e;
            tmp[e] = __float2bfloat16(k < K ? weight[c * K + k] : 0.f);
        }
        *reinterpret_cast<bf16x8*>(&wlds[c][k0]) = *reinterpret_cast<bf16x8*>(tmp);
    }

    __syncthreads();    // drains vmcnt (gload_lds) + lgkm (wlds writes)

    // ---- fragments ----
    // A (M=window, K): row = lane&15, k = (lane>>4)*8 + e  [+32*ks]
    const int arow = wuni * 16 + lo;
    bf16x8 afrag[2];
#pragma unroll
    for (int ks = 0; ks < 2; ++ks) {
        const int kb = hi * 8 + ks * 32;
        short a8[8];
#pragma unroll
        for (int e = 0; e < 8; ++e)
            a8[e] = f2bf(sh.xs[arow * K + kb + e]);   // pad region is zeroed/finite
        afrag[ks] = *reinterpret_cast<bf16x8*>(a8);
    }
    // B (K, N=channel): col = lane&15, k = (lane>>4)*8 + e  [+32*ks]
    bf16x8 bfrag[2][2];                           // [n][ks]
#pragma unroll
    for (int n = 0; n < 2; ++n)
#pragma unroll
        for (int ks = 0; ks < 2; ++ks)
            bfrag[n][ks] = *reinterpret_cast<const bf16x8*>(&wlds[n * 16 + lo][hi * 8 + ks * 32]);

    // ---- 4 MFMAs: D[16w x 32c] per wave ----
    f32x4 acc[2] = {f32x4{0,0,0,0}, f32x4{0,0,0,0}};
#pragma unroll
    for (int ks = 0; ks < 2; ++ks) {
#pragma unroll
        for (int n = 0; n < 2; ++n)
            acc[n] = __builtin_amdgcn_mfma_f32_16x16x32_bf16(afrag[ks], bfrag[n][ks], acc[n], 0, 0, 0);
    }

    __syncthreads();    // all A-frag reads of xs done -> safe to overlay cs

    // ---- scatter C to LDS: col=lane&15 (channel), row=(lane>>4)*4+reg (window) ----
#pragma unroll
    for (int n = 0; n < 2; ++n)
#pragma unroll
        for (int r = 0; r < 4; ++r)
            sh.cs[(n * 16 + lo) * 65 + (wuni * 16 + hi * 4 + r)] = acc[n][r];

    __syncthreads();

    // ---- coalesced store: wave wuni -> channels 8*wuni..+7, 256 B per plane ----
    const size_t w0 = b * (size_t)TILE;
#pragma unroll
    for (int cc = 0; cc < 8; ++cc) {
        const int c = wuni * 8 + cc;                       // SGPR-uniform
        out[(size_t)c * windows_nb + w0 + lane] = sh.cs[c * 65 + lane] + bias[c];
    }
}

// Known-good fallback (R9, 79.5 us) for unexpected sizes.
__global__ __launch_bounds__(128, 8) void conv2d_split2u(
    const float* __restrict__ enc_x, const float* __restrict__ weight,
    const float* __restrict__ bias, float* __restrict__ out, int windows_nb)
{
    __shared__ __align__(16) float xs[TILE_F];
    const int t = threadIdx.x, lane = t & 63, wid = t >> 6;
    const size_t b = blockIdx.x;
    const float* __restrict__ g = enc_x + b * (size_t)TILE_F;
    if (wid == 0) {
#pragma unroll
        for (int r = 0; r < 6; ++r)
            __builtin_amdgcn_global_load_lds(GPTR(g + r * 256 + lane * 4),
                                             LPTR(xs + r * 256 + lane * 4), 16, 0, 0);
    } else {
#pragma unroll
        for (int r = 6; r < 12; ++r)
            __builtin_amdgcn_global_load_lds(GPTR(g + r * 256 + lane * 4),
                                             LPTR(xs + r * 256 + lane * 4), 16, 0, 0);
        __builtin_amdgcn_global_load_lds(GPTR(g + 3072 + lane),
                                         LPTR(xs + 3072 + lane), 4, 0, 0);
    }
    asm volatile("s_waitcnt vmcnt(0)" ::: "memory");
    __builtin_amdgcn_s_barrier();
    const int c0 = __builtin_amdgcn_readfirstlane(wid) * 16;
    const float* __restrict__ wp = weight + c0 * K;
    float acc[16];
#pragma unroll
    for (int cc = 0; cc < 16; ++cc) acc[cc] = bias[c0 + cc];
    float x[25];
#pragma unroll
    for (int k = 0; k < 24; ++k) x[k] = xs[lane * K + k];
#pragma unroll 2
    for (int cc = 0; cc < 16; ++cc) {
        const float* __restrict__ wc = wp + cc * K;
        float a = acc[cc];
#pragma unroll
        for (int k = 0; k < 24; ++k) a = fmaf(x[k], wc[k], a);
        acc[cc] = a;
    }
#pragma unroll
    for (int k = 0; k < 25; ++k) x[k] = xs[lane * K + 24 + k];
#pragma unroll 2
    for (int cc = 0; cc < 16; ++cc) {
        const float* __restrict__ wc = wp + cc * K + 24;
        float a = acc[cc];
#pragma unroll
        for (int k = 0; k < 25; ++k) a = fmaf(x[k], wc[k], a);
        acc[cc] = a;
    }
    const size_t w = b * TILE + lane;
#pragma unroll
    for (int cc = 0; cc < 16; ++cc)
        out[(size_t)(c0 + cc) * windows_nb + w] = acc[cc];
}

extern "C" void kernel_launch(void* const* d_in, const int* in_sizes, int n_in,
                              void* d_out, int out_size, void* d_ws, size_t ws_size,
                              hipStream_t stream) {
    const float* enc_x  = (const float*)d_in[0];
    const float* weight = (const float*)d_in[1];   // [C,7,7] flat
    const float* bias   = (const float*)d_in[2];   // [C]
    float* out = (float*)d_out;

    const int windows_nb = in_sizes[0] / K;        // 1048576 expected

    if ((windows_nb % TILE) == 0) {
        conv2d_mfma<<<windows_nb / TILE, BLK, 0, stream>>>(enc_x, weight, bias, out, windows_nb);
    } else {
        conv2d_split2u<<<(windows_nb + TILE - 1) / TILE, 128, 0, stream>>>(enc_x, weight, bias, out, windows_nb);
    }
}

// Round 15
// 72.300 us; speedup vs baseline: 1.6407x; 1.1010x over previous
//
#include <hip/hip_runtime.h>
#include <hip/hip_bf16.h>
#include <stdint.h>

constexpr int K    = 49;             // 7x7 kernel flattened
constexpr int C    = 32;             // out channels
constexpr int TILE = 128;            // windows per block
constexpr int WPW  = 32;             // windows per wave
constexpr int RF   = WPW * K;        // 1568 floats staged per wave
constexpr int REG  = 1600;           // region floats (1568 + 32 tail slack)
constexpr int BLK  = 256;            // 4 waves

typedef short bf16x8 __attribute__((ext_vector_type(8)));
typedef float f32x4  __attribute__((ext_vector_type(4)));

#define GPTR(p) ((const __attribute__((address_space(1))) uint32_t*)(p))
#define LPTR(p) ((__attribute__((address_space(3))) uint32_t*)(p))
#define WAITV(n) asm volatile("s_waitcnt vmcnt(" #n ")" ::: "memory")

static __device__ __forceinline__ short f2bf(float f) {
    __hip_bfloat16 h = __float2bfloat16(f);      // RNE
    return __builtin_bit_cast(short, h);
}

// Independent per-wave pipelines: each wave stages ONLY its own 32 rows into
// a private LDS region and waits only on its own vmcnt. Zero barriers on the
// x-path (R9/R14 invariant ~80us traced to the block-wide stage drain
// phase-coupling all waves -> ~50% read-pipe duty).
__global__ __launch_bounds__(BLK) void conv2d_wavepipe(
    const float* __restrict__ enc_x,
    const float* __restrict__ weight,   // [C*K]
    const float* __restrict__ bias,     // [C]
    float* __restrict__ out,            // [C * windows_nb]
    int windows_nb)
{
    __shared__ __align__(16) float xs[4 * REG];            // 25600 B, 4 private regions
    __shared__ __align__(16) __hip_bfloat16 wlds[C][72];   // 4608 B bf16 palette

    const int t    = threadIdx.x;
    const int lane = t & 63;
    const int lo   = lane & 15, hi = lane >> 4;
    const int wuni = __builtin_amdgcn_readfirstlane(t >> 6);  // SGPR wave id
    const size_t b = blockIdx.x;

    // ---- weight palette (R14-proven), before ANY x-VMEM is issued ----
    {
        const int c  = t >> 3;
        const int k0 = (t & 7) * 8;
        __hip_bfloat16 tmp[8];
#pragma unroll
        for (int e = 0; e < 8; ++e) {
            const int k = k0 + e;
            tmp[e] = __float2bfloat16(k < K ? weight[c * K + k] : 0.f);
        }
        *reinterpret_cast<bf16x8*>(&wlds[c][k0]) = *reinterpret_cast<bf16x8*>(tmp);
    }
    __syncthreads();     // orders only the tiny palette; x-stage not yet issued

    // ---------- per-wave independent from here on ----------
    float* __restrict__ xr = xs + wuni * REG;                       // private region
    const float* __restrict__ gw = enc_x + b * (size_t)(TILE * K) + wuni * RF;

    // stage own 6272 B: 6 x (64 lanes x 16 B) + clamped 4 B tail (lanes>=32
    // write dup junk into floats 1568..1599 slack -> never read as k<49 data)
#pragma unroll
    for (int r = 0; r < 6; ++r)
        __builtin_amdgcn_global_load_lds(GPTR(gw + r * 256 + lane * 4),
                                         LPTR(xr + r * 256 + lane * 4), 16, 0, 0);
    __builtin_amdgcn_global_load_lds(GPTR(gw + 1536 + (lane < 32 ? lane : 31)),
                                     LPTR(xr + 1536 + lane), 4, 0, 0);

    WAITV(0);                                  // waits OWN 7 ops only (no barrier)
    __builtin_amdgcn_sched_barrier(0);

    // ---- A fragments (M=own windows, K): row = m*16+lo, k = hi*8+ks*32+e ----
    bf16x8 af[2][2];                           // [m][ks]
#pragma unroll
    for (int m = 0; m < 2; ++m)
#pragma unroll
        for (int ks = 0; ks < 2; ++ks) {
            const int row = m * 16 + lo;
            short a8[8];
#pragma unroll
            for (int e = 0; e < 8; ++e) {
                const int kk = hi * 8 + ks * 32 + e;
                float v;
                if (ks == 0) v = xr[row * K + kk];                    // k<=31 valid
                else         v = (hi * 8 + e < 17) ? xr[row * K + kk] : 0.f;  // k<49
                a8[e] = f2bf(v);
            }
            af[m][ks] = *reinterpret_cast<bf16x8*>(a8);
        }

    // ---- B fragments from palette: 16B-aligned ds_read_b128 ----
    bf16x8 bf_[2][2];                          // [n][ks]
#pragma unroll
    for (int n = 0; n < 2; ++n)
#pragma unroll
        for (int ks = 0; ks < 2; ++ks)
            bf_[n][ks] = *reinterpret_cast<const bf16x8*>(&wlds[n * 16 + lo][hi * 8 + ks * 32]);

    // ---- 8 MFMAs: 32 windows x 32 channels per wave ----
    f32x4 acc[2][2];
#pragma unroll
    for (int m = 0; m < 2; ++m)
#pragma unroll
        for (int n = 0; n < 2; ++n) acc[m][n] = f32x4{0.f, 0.f, 0.f, 0.f};
#pragma unroll
    for (int ks = 0; ks < 2; ++ks)
#pragma unroll
        for (int m = 0; m < 2; ++m)
#pragma unroll
            for (int n = 0; n < 2; ++n)
                acc[m][n] = __builtin_amdgcn_mfma_f32_16x16x32_bf16(
                    af[m][ks], bf_[n][ks], acc[m][n], 0, 0, 0);

    // ---- epilogue: transpose via private cs overlay of own (dead) region ----
    asm volatile("" ::: "memory");             // keep A ds_reads before overlay writes
    float* __restrict__ cw = xr;               // [32 c][33] = 1056 floats <= REG
#pragma unroll
    for (int m = 0; m < 2; ++m)
#pragma unroll
        for (int n = 0; n < 2; ++n)
#pragma unroll
            for (int r = 0; r < 4; ++r)
                cw[(n * 16 + lo) * 33 + (m * 16 + hi * 4 + r)] = acc[m][n][r];

    // ---- stores: 2 channels x 32 windows per instr, 16 instrs, no barrier ----
    const size_t wbase = b * (size_t)TILE + wuni * WPW;
    const int win = lane & 31;
    const int ch  = lane >> 5;                 // 0/1
#pragma unroll
    for (int ci = 0; ci < 16; ++ci) {
        const int c_ = 2 * ci + ch;
        out[(size_t)c_ * windows_nb + wbase + win] = cw[c_ * 33 + win] + bias[c_];
    }
}

// Known-good fallback (R9, 79.5 us) for unexpected sizes.
__global__ __launch_bounds__(128, 8) void conv2d_split2u(
    const float* __restrict__ enc_x, const float* __restrict__ weight,
    const float* __restrict__ bias, float* __restrict__ out, int windows_nb)
{
    __shared__ __align__(16) float xsf[64 * K];
    const int t = threadIdx.x, lane = t & 63, wid = t >> 6;
    const size_t b = blockIdx.x;
    const float* __restrict__ g = enc_x + b * (size_t)(64 * K);
    if (wid == 0) {
#pragma unroll
        for (int r = 0; r < 6; ++r)
            __builtin_amdgcn_global_load_lds(GPTR(g + r * 256 + lane * 4),
                                             LPTR(xsf + r * 256 + lane * 4), 16, 0, 0);
    } else {
#pragma unroll
        for (int r = 6; r < 12; ++r)
            __builtin_amdgcn_global_load_lds(GPTR(g + r * 256 + lane * 4),
                                             LPTR(xsf + r * 256 + lane * 4), 16, 0, 0);
        __builtin_amdgcn_global_load_lds(GPTR(g + 3072 + lane),
                                         LPTR(xsf + 3072 + lane), 4, 0, 0);
    }
    asm volatile("s_waitcnt vmcnt(0)" ::: "memory");
    __builtin_amdgcn_s_barrier();
    const int c0 = __builtin_amdgcn_readfirstlane(wid) * 16;
    const float* __restrict__ wp = weight + c0 * K;
    float acc[16];
#pragma unroll
    for (int cc = 0; cc < 16; ++cc) acc[cc] = bias[c0 + cc];
    float x[25];
#pragma unroll
    for (int k = 0; k < 24; ++k) x[k] = xsf[lane * K + k];
#pragma unroll 2
    for (int cc = 0; cc < 16; ++cc) {
        const float* __restrict__ wc = wp + cc * K;
        float a = acc[cc];
#pragma unroll
        for (int k = 0; k < 24; ++k) a = fmaf(x[k], wc[k], a);
        acc[cc] = a;
    }
#pragma unroll
    for (int k = 0; k < 25; ++k) x[k] = xsf[lane * K + 24 + k];
#pragma unroll 2
    for (int cc = 0; cc < 16; ++cc) {
        const float* __restrict__ wc = wp + cc * K + 24;
        float a = acc[cc];
#pragma unroll
        for (int k = 0; k < 25; ++k) a = fmaf(x[k], wc[k], a);
        acc[cc] = a;
    }
    const size_t w = b * 64 + lane;
#pragma unroll
    for (int cc = 0; cc < 16; ++cc)
        out[(size_t)(c0 + cc) * windows_nb + w] = acc[cc];
}

extern "C" void kernel_launch(void* const* d_in, const int* in_sizes, int n_in,
                              void* d_out, int out_size, void* d_ws, size_t ws_size,
                              hipStream_t stream) {
    const float* enc_x  = (const float*)d_in[0];
    const float* weight = (const float*)d_in[1];   // [C,7,7] flat
    const float* bias   = (const float*)d_in[2];   // [C]
    float* out = (float*)d_out;

    const int windows_nb = in_sizes[0] / K;        // 1048576 expected

    if ((windows_nb % TILE) == 0) {
        conv2d_wavepipe<<<windows_nb / TILE, BLK, 0, stream>>>(enc_x, weight, bias, out, windows_nb);
    } else {
        conv2d_split2u<<<(windows_nb + 63) / 64, 128, 0, stream>>>(enc_x, weight, bias, out, windows_nb);
    }
}